// Round 1
// baseline (195.714 us; speedup 1.0000x reference)
//
#include <hip/hip_runtime.h>

#define EPSBN 1e-3f

typedef unsigned short ushort_t;
typedef __attribute__((ext_vector_type(8))) short bf8;   // 8 bf16 = 4 VGPRs
typedef __attribute__((ext_vector_type(4))) float f4;

__device__ __forceinline__ float sigmoidf_(float z) {
  return 1.0f / (1.0f + expf(-z));
}

__device__ __forceinline__ ushort_t f2bf(float x) {  // RTNE
  union { float f; unsigned u; } v; v.f = x;
  unsigned r = (v.u + 0x7fffu + ((v.u >> 16) & 1u)) >> 16;
  return (ushort_t)r;
}

// ---------------- K: prep — coalesced channel sums + f32->bf16 pad-8 repack ----
// grid: 512 blocks = b*8+seg; each block owns 2048 pixels (4 phases x 512 px).
// Loads are fully coalesced float4; LDS bounce gives exact per-channel sums and
// coalesced 16B/pixel bf16 stores to xb16 [pix][8] (ch 6,7 zero).
__global__ __launch_bounds__(256)
void k_prep(const float* __restrict__ x, float* __restrict__ part,
            ushort_t* __restrict__ xb16) {
  const int bid = blockIdx.x;
  const int tid = threadIdx.x;
  __shared__ __align__(16) float raw[3072];   // 512 px * 6 ch
  __shared__ float red[4][6];
  float acc[6] = {0.f, 0.f, 0.f, 0.f, 0.f, 0.f};
  const size_t pixbase = (size_t)(bid >> 3) * 16384 + (size_t)(bid & 7) * 2048;
  const float* xq = x + pixbase * 6;
  ushort_t* oq = xb16 + pixbase * 8;
  for (int ph = 0; ph < 4; ++ph) {
    const float4* src = (const float4*)(xq + (size_t)ph * 3072);
#pragma unroll
    for (int i = 0; i < 3; ++i)
      *(float4*)(raw + (i * 256 + tid) * 4) = src[i * 256 + tid];
    __syncthreads();
#pragma unroll
    for (int h = 0; h < 2; ++h) {
      const int pix = h * 256 + tid;
      const float* r = raw + pix * 6;
      const float2 p01 = *(const float2*)(r);
      const float2 p23 = *(const float2*)(r + 2);
      const float2 p45 = *(const float2*)(r + 4);
      acc[0] += p01.x; acc[1] += p01.y; acc[2] += p23.x;
      acc[3] += p23.y; acc[4] += p45.x; acc[5] += p45.y;
      uint4 u;
      u.x = (unsigned)f2bf(p01.x) | ((unsigned)f2bf(p01.y) << 16);
      u.y = (unsigned)f2bf(p23.x) | ((unsigned)f2bf(p23.y) << 16);
      u.z = (unsigned)f2bf(p45.x) | ((unsigned)f2bf(p45.y) << 16);
      u.w = 0u;
      *(uint4*)(oq + ((size_t)ph * 512 + pix) * 8) = u;
    }
    __syncthreads();
  }
  const int lane = tid & 63, w = tid >> 6;
#pragma unroll
  for (int c = 0; c < 6; ++c)
    for (int off = 32; off > 0; off >>= 1) acc[c] += __shfl_down(acc[c], off, 64);
  if (lane == 0) {
#pragma unroll
    for (int c = 0; c < 6; ++c) red[w][c] = acc[c];
  }
  __syncthreads();
  if (tid < 6)
    part[bid * 6 + tid] = red[0][tid] + red[1][tid] + red[2][tid] + red[3][tid];
}

// ------------- K: conv1 (fused route1/buildk1) MFMA + BN + relu + pool + mean1 -
// grid: 64 b x 4 row-tiles x 2 col-tiles = 512 blocks. Stages pre-packed bf16.
__global__ __launch_bounds__(256)
void k_conv1(const ushort_t* __restrict__ xb16, const float* __restrict__ meanx_part,
             const float* __restrict__ experts1,
             const float* __restrict__ rw, const float* __restrict__ rbias,
             const float* __restrict__ gamma, const float* __restrict__ beta,
             const float* __restrict__ bnmean, const float* __restrict__ bnvar,
             ushort_t* __restrict__ p1b, float* __restrict__ part_m1) {
  const int bid = blockIdx.x;
  const int b = bid >> 3;
  const int tyi = (bid >> 1) & 3;
  const int txi = bid & 1;
  __shared__ __align__(16) ushort_t patch[34 * 68 * 8];  // 36,992 B
  __shared__ float route_s[3];
  __shared__ float mred[4][32];
  const int tid = threadIdx.x;
  const ushort_t* xb = xb16 + (size_t)b * 131072;  // 128*128*8

  if (tid < 3) {
    float z = rbias[tid];
    for (int c = 0; c < 6; ++c) {
      float s = 0.f;
#pragma unroll
      for (int k = 0; k < 8; ++k) s += meanx_part[(b * 8 + k) * 6 + c];
      z += (s * (1.0f / 16384.0f)) * rw[c * 3 + tid];
    }
    route_s[tid] = sigmoidf_(z);
  }

  for (int v = tid; v < 34 * 68; v += 256) {
    const int ry = v / 68, p = v - ry * 68;
    const int gy = tyi * 32 - 1 + ry, gx = txi * 64 - 1 + p;
    uint4 u = make_uint4(0u, 0u, 0u, 0u);
    if (((unsigned)gy < 128u) && ((unsigned)gx < 128u))
      u = *(const uint4*)(xb + ((size_t)(gy * 128 + gx)) * 8);
    *(uint4*)(patch + (size_t)v * 8) = u;
  }
  __syncthreads();

  const int w = tid >> 6;
  const int lane = tid & 63;
  const int lx = lane & 15, lg = lane >> 4;

  const float r0 = route_s[0], r1 = route_s[1], r2 = route_s[2];
  const int co0 = lx, co1 = 16 + lx;
  const float inv0 = gamma[co0] * rsqrtf(bnvar[co0] + EPSBN);
  const float bias0 = beta[co0] - bnmean[co0] * inv0;
  const float inv1 = gamma[co1] * rsqrtf(bnvar[co1] + EPSBN);
  const float bias1 = beta[co1] - bnmean[co1] * inv1;

  // build B fragments in-register: Bf[ky][nt][j] = W'[kx=lg][ci=j][co=nt*16+lx]
  bf8 Bf[3][2];
#pragma unroll
  for (int ky = 0; ky < 3; ++ky) {
#pragma unroll
    for (int nt = 0; nt < 2; ++nt) {
      const int co = nt * 16 + lx;
      const float inv = nt ? inv1 : inv0;
#pragma unroll
      for (int j = 0; j < 8; ++j) {
        float val = 0.f;
        if (j < 6 && lg < 3) {
          const int idx = ((ky * 3 + lg) * 6 + j) * 32 + co;
          val = (r0 * experts1[idx] + r1 * experts1[1728 + idx] +
                 r2 * experts1[3456 + idx]) * inv;
        }
        Bf[ky][nt][j] = (short)f2bf(val);
      }
    }
  }

  float msum0 = 0.f, msum1 = 0.f;

#pragma unroll
  for (int xt = 0; xt < 4; ++xt) {
    bf8 Af[10];
#pragma unroll
    for (int r = 0; r < 10; ++r)
      Af[r] = *(const bf8*)(patch + ((size_t)(w * 8 + r) * 68 + xt * 16 + lx + lg) * 8);
#pragma unroll
    for (int rp = 0; rp < 4; ++rp) {
      const int prow = tyi * 16 + w * 4 + rp;
      f4 acc0[2], acc1[2];
#pragma unroll
      for (int nt = 0; nt < 2; ++nt) {
        acc0[nt] = (f4){0.f, 0.f, 0.f, 0.f};
        acc1[nt] = (f4){0.f, 0.f, 0.f, 0.f};
      }
#pragma unroll
      for (int ky = 0; ky < 3; ++ky) {
#pragma unroll
        for (int nt = 0; nt < 2; ++nt) {
          acc0[nt] = __builtin_amdgcn_mfma_f32_16x16x32_bf16(Af[rp * 2 + ky], Bf[ky][nt], acc0[nt], 0, 0, 0);
          acc1[nt] = __builtin_amdgcn_mfma_f32_16x16x32_bf16(Af[rp * 2 + ky + 1], Bf[ky][nt], acc1[nt], 0, 0, 0);
        }
      }
#pragma unroll
      for (int nt = 0; nt < 2; ++nt) {
        const float bias = nt ? bias1 : bias0;
        const int co = nt * 16 + lx;
#pragma unroll
        for (int q = 0; q < 2; ++q) {
          const float m0 = fmaxf(acc0[nt][2 * q] + bias, 0.f);
          const float m1 = fmaxf(acc0[nt][2 * q + 1] + bias, 0.f);
          const float m2 = fmaxf(acc1[nt][2 * q] + bias, 0.f);
          const float m3 = fmaxf(acc1[nt][2 * q + 1] + bias, 0.f);
          const float mx = fmaxf(fmaxf(m0, m1), fmaxf(m2, m3));
          if (nt) msum1 += mx; else msum0 += mx;
          const int pcol = txi * 32 + xt * 8 + lg * 2 + q;
          p1b[(((size_t)b * 64 + prow) * 64 + pcol) * 32 + co] = f2bf(mx);
        }
      }
    }
  }

  msum0 += __shfl_xor(msum0, 16, 64);
  msum0 += __shfl_xor(msum0, 32, 64);
  msum1 += __shfl_xor(msum1, 16, 64);
  msum1 += __shfl_xor(msum1, 32, 64);
  if (lg == 0) {
    mred[w][lx] = msum0;
    mred[w][16 + lx] = msum1;
  }
  __syncthreads();
  if (tid < 32) {
    part_m1[(size_t)bid * 32 + tid] =
        mred[0][tid] + mred[1][tid] + mred[2][tid] + mred[3][tid];
  }
}

// ------------- K: SE1 + route2 + build k2' bf16 [b][tap][co][ci] (192 blocks) --
__global__ void k_buildk2(const float* __restrict__ part_m1,
                          const float* __restrict__ experts2,
                          const float* __restrict__ rw, const float* __restrict__ rb,
                          const float* __restrict__ w1, const float* __restrict__ w2,
                          const float* __restrict__ gamma, const float* __restrict__ var,
                          ushort_t* __restrict__ k2pb) {
  const int b = blockIdx.x / 3;
  const int seg = blockIdx.x - b * 3;
  const int tid = threadIdx.x;
  __shared__ float m1[32], h[2], s1[32], route[3];
  if (tid < 32) {
    float s = 0.f;
#pragma unroll
    for (int k = 0; k < 8; ++k) s += part_m1[(size_t)(b * 8 + k) * 32 + tid];
    m1[tid] = s * (1.0f / 4096.0f);
  }
  __syncthreads();
  if (tid < 2) {
    float z = 0.f;
    for (int c = 0; c < 32; ++c) z += m1[c] * w1[c * 2 + tid];
    h[tid] = fmaxf(z, 0.f);
  }
  __syncthreads();
  if (tid < 32) s1[tid] = sigmoidf_(h[0] * w2[tid] + h[1] * w2[32 + tid]);
  __syncthreads();
  if (tid < 3) {
    float z = rb[tid];
    for (int c = 0; c < 32; ++c) z += m1[c] * s1[c] * rw[c * 3 + tid];
    route[tid] = sigmoidf_(z);
  }
  __syncthreads();
  const float r0 = route[0], r1 = route[1], r2 = route[2];
  const int t_lo = seg * 6144, t_hi = t_lo + 6144;
  for (int t = t_lo + tid; t < t_hi; t += 256) {
    const int co = t & 63;
    const int ci = (t >> 6) & 31;
    const int tap = t >> 11;
    const float inv = gamma[co] * rsqrtf(var[co] + EPSBN);
    const float v = r0 * experts2[t] + r1 * experts2[18432 + t] + r2 * experts2[2 * 18432 + t];
    k2pb[(size_t)b * 18432 + ((size_t)tap * 64 + co) * 32 + ci] = f2bf(v * s1[ci] * inv);
  }
}

// ------------- K: conv2 MFMA + BN + relu + pool + S3 boundary aggregates -------
// grid: 64 b x 16 tiles = 1024 blocks. Each block computes ALL 64 couts
// (two passes over Bs halves so LDS stays < 64 KB). p1b is staged ONCE per tile
// (was twice with the cog split). Emits 9 aggregates per (tile, co) into
// part_s3[bi*576 + agg*64 + co].
__global__ __launch_bounds__(256)
void k_conv2(const ushort_t* __restrict__ p1b, const ushort_t* __restrict__ k2pb,
             const float* __restrict__ gamma, const float* __restrict__ beta,
             const float* __restrict__ bnmean, const float* __restrict__ bnvar,
             float* __restrict__ part_s3) {
  const int bi = blockIdx.x;
  const int b = bi >> 4;
  const int tile = bi & 15;
  const int ty = tile >> 2, tx = tile & 3;
  __shared__ __align__(16) short smem[12960 + 11520];  // As + Bs-half = 48,960 B
  short* As = smem;
  short* Bs = smem + 12960;
  const int tid = threadIdx.x;

  const ushort_t* pb = p1b + (size_t)b * 131072;
  for (int v = tid; v < 1296; v += 256) {
    const int cell = v >> 2, part = v & 3;
    const int ly = cell / 18, lx2 = cell - ly * 18;
    const int gy = ty * 16 - 1 + ly, gx = tx * 16 - 1 + lx2;
    uint4 d = make_uint4(0u, 0u, 0u, 0u);
    if (((unsigned)gy < 64u) && ((unsigned)gx < 64u))
      d = *(const uint4*)(pb + (((size_t)gy << 6) + gx) * 32 + part * 8);
    *(uint4*)(As + (ly * 18 + lx2) * 40 + part * 8) = d;
  }

  const int w = tid >> 6;
  const int lane = tid & 63;
  const int lx = lane & 15, lg = lane >> 4;

  float agg[4][9];   // [cg*2+nt][agg]
#pragma unroll
  for (int g = 0; g < 4; ++g)
#pragma unroll
    for (int a = 0; a < 9; ++a) agg[g][a] = 0.f;

  for (int cg = 0; cg < 2; ++cg) {
    if (cg) __syncthreads();  // pass-0 reads complete before Bs overwrite
    for (int v = tid; v < 1152; v += 256) {
      const int r = v >> 2, part = v & 3;
      const int t = r >> 5, n = r & 31;
      const uint4 d = *(const uint4*)(k2pb + (size_t)b * 18432 +
                                      ((size_t)(t * 64 + cg * 32 + n)) * 32 + part * 8);
      *(uint4*)(Bs + r * 40 + part * 8) = d;
    }
    __syncthreads();

    f4 acc[4][2];
#pragma unroll
    for (int mt = 0; mt < 4; ++mt) {
      acc[mt][0] = (f4){0.f, 0.f, 0.f, 0.f};
      acc[mt][1] = (f4){0.f, 0.f, 0.f, 0.f};
    }

#pragma unroll
    for (int kx = 0; kx < 3; ++kx) {
      bf8 Af[6];
#pragma unroll
      for (int r = 0; r < 6; ++r)
        Af[r] = *(const bf8*)(As + ((4 * w + r) * 18 + lx + kx) * 40 + (lg << 3));
#pragma unroll
      for (int ky = 0; ky < 3; ++ky) {
        const int t = ky * 3 + kx;
        const bf8 Bf0 = *(const bf8*)(Bs + ((t << 5) + lx) * 40 + (lg << 3));
        const bf8 Bf1 = *(const bf8*)(Bs + ((t << 5) + 16 + lx) * 40 + (lg << 3));
#pragma unroll
        for (int mt = 0; mt < 4; ++mt) {
          acc[mt][0] = __builtin_amdgcn_mfma_f32_16x16x32_bf16(Af[ky + mt], Bf0, acc[mt][0], 0, 0, 0);
          acc[mt][1] = __builtin_amdgcn_mfma_f32_16x16x32_bf16(Af[ky + mt], Bf1, acc[mt][1], 0, 0, 0);
        }
      }
    }

    float inv[2], bias[2];
#pragma unroll
    for (int nt = 0; nt < 2; ++nt) {
      const int co = cg * 32 + nt * 16 + lx;
      inv[nt] = gamma[co] * rsqrtf(bnvar[co] + EPSBN);
      bias[nt] = beta[co] - bnmean[co] * inv[nt];
    }
#pragma unroll
    for (int half = 0; half < 2; ++half) {
      const int prow = ty * 8 + 2 * w + half;
      const bool rT = (prow == 0), rB = (prow == 31);
#pragma unroll
      for (int q = 0; q < 2; ++q) {
        const int pcol = tx * 8 + 2 * lg + q;
        const bool cL = (pcol == 0), cR = (pcol == 31);
#pragma unroll
        for (int nt = 0; nt < 2; ++nt) {
          const float m0 = fmaxf(acc[2 * half][nt][2 * q] + bias[nt], 0.f);
          const float m1 = fmaxf(acc[2 * half][nt][2 * q + 1] + bias[nt], 0.f);
          const float m2 = fmaxf(acc[2 * half + 1][nt][2 * q] + bias[nt], 0.f);
          const float m3 = fmaxf(acc[2 * half + 1][nt][2 * q + 1] + bias[nt], 0.f);
          const float mx = fmaxf(fmaxf(m0, m1), fmaxf(m2, m3));
          float* ag = agg[cg * 2 + nt];
          ag[0] += mx;
          if (rT) ag[1] += mx;
          if (rB) ag[2] += mx;
          if (cL) ag[3] += mx;
          if (cR) ag[4] += mx;
          if (rT && cL) ag[5] += mx;  // k00
          if (rT && cR) ag[6] += mx;  // k01
          if (rB && cL) ag[7] += mx;  // k10
          if (rB && cR) ag[8] += mx;  // k11
        }
      }
    }
  }

#pragma unroll
  for (int g = 0; g < 4; ++g)
#pragma unroll
    for (int a = 0; a < 9; ++a) {
      float vv = agg[g][a];
      vv += __shfl_xor(vv, 16, 64);
      vv += __shfl_xor(vv, 32, 64);
      agg[g][a] = vv;
    }
  __syncthreads();  // done with As/Bs; reuse smem for reduction
  float* sred = (float*)smem;  // [w][g][lx][agg] = [4][4][16][9] = 9216 B
  if (lg == 0) {
#pragma unroll
    for (int g = 0; g < 4; ++g)
#pragma unroll
      for (int a = 0; a < 9; ++a)
        sred[((w * 4 + g) * 16 + lx) * 9 + a] = agg[g][a];
  }
  __syncthreads();
  for (int v = tid; v < 576; v += 256) {
    const int a = v >> 6;          // aggregate 0..8
    const int co = v & 63;
    const int g = co >> 4, lxx = co & 15;
    float s = 0.f;
#pragma unroll
    for (int ww = 0; ww < 4; ++ww) s += sred[((ww * 4 + g) * 16 + lxx) * 9 + a];
    part_s3[(size_t)bi * 576 + v] = s;
  }
}

// ------------- K: S3 reconstruct + SE2 + route3 + contraction + BN3 ------------
__global__ __launch_bounds__(512)
void k_final(const float* __restrict__ part_s3, const float* __restrict__ experts3,
             const float* __restrict__ rw, const float* __restrict__ rb,
             const float* __restrict__ w1, const float* __restrict__ w2,
             const float* __restrict__ gamma, const float* __restrict__ beta,
             const float* __restrict__ bnmean, const float* __restrict__ bnvar,
             float* __restrict__ out) {
  const int b = blockIdx.x;
  const int tid = threadIdx.x;
  __shared__ float AG[9][64], Sp[9][64], m2[64], h[4], s2[64], route[3], redf[4][128];

  for (int v = tid; v < 576; v += 512) {
    const int a = v >> 6, ci = v & 63;
    float s = 0.f;
#pragma unroll
    for (int tile = 0; tile < 16; ++tile)
      s += part_s3[(size_t)(b * 16 + tile) * 576 + a * 64 + ci];
    AG[a][ci] = s;
  }
  __syncthreads();
  if (tid < 64) m2[tid] = AG[0][tid] * (1.0f / 1024.0f);
  __syncthreads();
  if (tid < 4) {
    float z = 0.f;
    for (int c = 0; c < 64; ++c) z += m2[c] * w1[c * 4 + tid];
    h[tid] = fmaxf(z, 0.f);
  }
  __syncthreads();
  if (tid < 64) {
    float z = 0.f;
#pragma unroll
    for (int j = 0; j < 4; ++j) z += h[j] * w2[j * 64 + tid];
    s2[tid] = sigmoidf_(z);
  }
  __syncthreads();
  if (tid < 3) {
    float z = rb[tid];
    for (int c = 0; c < 64; ++c) z += m2[c] * s2[c] * rw[c * 3 + tid];
    route[tid] = sigmoidf_(z);
  }
  __syncthreads();
  // reconstruct shifted sums: S = T - A[ky] - B[kx] + AB[ky][kx]
  for (int v = tid; v < 576; v += 512) {
    const int tap = v >> 6, ci = v & 63;
    const int ky = tap / 3, kx = tap - 3 * ky;
    const float T = AG[0][ci];
    const float A = (ky == 0) ? AG[2][ci] : ((ky == 2) ? AG[1][ci] : 0.f);
    const float B = (kx == 0) ? AG[4][ci] : ((kx == 2) ? AG[3][ci] : 0.f);
    float AB = 0.f;
    if (ky == 0 && kx == 0) AB = AG[8][ci];        // k11
    else if (ky == 0 && kx == 2) AB = AG[7][ci];   // k10
    else if (ky == 2 && kx == 0) AB = AG[6][ci];   // k01
    else if (ky == 2 && kx == 2) AB = AG[5][ci];   // k00
    Sp[tap][ci] = (T - A - B + AB) * s2[ci];
  }
  __syncthreads();

  const int co = tid & 127;
  const int quarter = tid >> 7;
  const int tap_lo = (quarter == 0) ? 0 : (2 * quarter + 1);
  const int tap_hi = tap_lo + ((quarter == 0) ? 3 : 2);
  // single pass, 3 independent FMA chains (one per expert)
  float me0 = 0.f, me1 = 0.f, me2 = 0.f;
  for (int tap = tap_lo; tap < tap_hi; ++tap) {
    const float* E0 = experts3 + ((size_t)tap * 64) * 128 + co;
    const float* E1 = E0 + (size_t)9 * 64 * 128;
    const float* E2 = E1 + (size_t)9 * 64 * 128;
#pragma unroll 16
    for (int ci = 0; ci < 64; ++ci) {
      const float s = Sp[tap][ci];
      me0 = fmaf(E0[(size_t)ci * 128], s, me0);
      me1 = fmaf(E1[(size_t)ci * 128], s, me1);
      me2 = fmaf(E2[(size_t)ci * 128], s, me2);
    }
  }
  redf[quarter][co] = route[0] * me0 + route[1] * me1 + route[2] * me2;
  __syncthreads();
  if (tid < 128) {
    const float total = redf[0][tid] + redf[1][tid] + redf[2][tid] + redf[3][tid];
    const float inv = gamma[tid] * rsqrtf(bnvar[tid] + EPSBN);
    out[(size_t)b * 128 + tid] = total * (1.0f / 1024.0f) * inv + (beta[tid] - bnmean[tid] * inv);
  }
}

extern "C" void kernel_launch(void* const* d_in, const int* in_sizes, int n_in,
                              void* d_out, int out_size, void* d_ws, size_t ws_size,
                              hipStream_t stream) {
  const float* x        = (const float*)d_in[0];
  const float* experts1 = (const float*)d_in[1];
  const float* rw1      = (const float*)d_in[2];
  const float* rb1      = (const float*)d_in[3];
  const float* g1  = (const float*)d_in[4];
  const float* be1 = (const float*)d_in[5];
  const float* mu1 = (const float*)d_in[6];
  const float* va1 = (const float*)d_in[7];
  const float* sw1a = (const float*)d_in[8];
  const float* sw1b = (const float*)d_in[9];
  const float* experts2 = (const float*)d_in[10];
  const float* rw2 = (const float*)d_in[11];
  const float* rb2 = (const float*)d_in[12];
  const float* g2  = (const float*)d_in[13];
  const float* be2 = (const float*)d_in[14];
  const float* mu2 = (const float*)d_in[15];
  const float* va2 = (const float*)d_in[16];
  const float* sw2a = (const float*)d_in[17];
  const float* sw2b = (const float*)d_in[18];
  const float* experts3 = (const float*)d_in[19];
  const float* rw3 = (const float*)d_in[20];
  const float* rb3 = (const float*)d_in[21];
  const float* g3  = (const float*)d_in[22];
  const float* be3 = (const float*)d_in[23];
  const float* mu3 = (const float*)d_in[24];
  const float* va3 = (const float*)d_in[25];
  float* out = (float*)d_out;
  float* ws = (float*)d_ws;

  // workspace layout (float offsets, all 16B-aligned):
  float* meanx_part = ws;                           // 3,072        [512][6]
  float* part_m1    = ws + 3072;                    // 16,384       [512][32]
  ushort_t* k2pb    = (ushort_t*)(ws + 19456);      // 1,179,648 shorts = 589,824 fl
  float* part_s3    = ws + 609280;                  // 589,824      [1024][576]
  ushort_t* p1b     = (ushort_t*)(ws + 1199104);    // 8,388,608 shorts = 4,194,304 fl
  ushort_t* xb16    = (ushort_t*)(ws + 5393408);    // 8,388,608 shorts = 4,194,304 fl
  // end: 9,587,712 floats = 38.4 MB

  hipLaunchKernelGGL(k_prep, dim3(512), dim3(256), 0, stream, x, meanx_part, xb16);
  hipLaunchKernelGGL(k_conv1, dim3(512), dim3(256), 0, stream,
                     xb16, meanx_part, experts1, rw1, rb1, g1, be1, mu1, va1, p1b, part_m1);
  hipLaunchKernelGGL(k_buildk2, dim3(192), dim3(256), 0, stream,
                     part_m1, experts2, rw2, rb2, sw1a, sw1b, g2, va2, k2pb);
  hipLaunchKernelGGL(k_conv2, dim3(1024), dim3(256), 0, stream,
                     p1b, k2pb, g2, be2, mu2, va2, part_s3);
  hipLaunchKernelGGL(k_final, dim3(64), dim3(512), 0, stream,
                     part_s3, experts3, rw3, rb3, sw2a, sw2b, g3, be3, mu3, va3, out);
}